// Round 15
// baseline (188.529 us; speedup 1.0000x reference)
//
#include <hip/hip_runtime.h>
#include <math.h>

typedef _Float16 f16x8 __attribute__((ext_vector_type(8)));
typedef float f32x4 __attribute__((ext_vector_type(4)));
typedef unsigned int u32;
typedef unsigned long long u64;

#define NBATCH 32
#define CIN    64
#define COUT   192
#define HWD    56
#define KR     4
#define NKQ    14

#define WS_W_OFF  1024

#define SBAR()  do { __builtin_amdgcn_s_barrier(); asm volatile("" ::: "memory"); } while(0)
#define WAITL() asm volatile("s_waitcnt lgkmcnt(0)" ::: "memory")

struct KArgs {
    float bt[49];
    float einit[7];
};

// AT transposed: ATT[v][u] = AT[u][v]
__device__ const float ATT[7][5] = {
    {1,0,0,0,0},{1,1,1,1,1},{1,-1,1,-1,1},{1,2,4,8,16},{1,-2,4,-8,16},{1,3,9,27,81},{0,0,0,0,1}};

// ---------------- Host: Householder QR lstsq for BT (f64) + range flag ----------------
static void host_compute_bt(KArgs* ka, bool* dual) {
    const double ATd[5][7] = {
        {1,1,1,1,1,1,0},{0,1,-1,2,-2,3,0},{0,1,1,4,4,9,0},{0,1,-1,8,-8,27,0},{0,1,1,16,16,81,1}};
    const double pts[6] = {0.0,1.0,-1.0,2.0,-2.0,3.0};
    double G[7][3];
    for (int i=0;i<6;i++){ G[i][0]=1.0; G[i][1]=pts[i]; G[i][2]=pts[i]*pts[i]; }
    G[6][0]=0.0; G[6][1]=0.0; G[6][2]=1.0;
    double M[15][7], T[15][7];
    for (int p=0;p<3;p++)
        for (int u=0;u<5;u++)
            for (int v=0;v<7;v++)
                M[5*p+u][v] = ATd[u][v]*G[v][p];
    for (int i=0;i<15;i++) for (int j=0;j<7;j++) T[i][j]=0.0;
    for (int p=0;p<3;p++) for (int kk=0;kk<5;kk++) T[5*p+kk][kk+p]=1.0;
    for (int j=0;j<7;j++){
        double sig=0.0; for (int i=j;i<15;i++) sig += M[i][j]*M[i][j];
        double nrm = sqrt(sig);
        double ajj = M[j][j];
        double alpha = (ajj > 0.0) ? -nrm : nrm;
        double v[15];
        v[j] = ajj - alpha;
        for (int i=j+1;i<15;i++) v[i] = M[i][j];
        double vtv = sig - 2.0*alpha*ajj + alpha*alpha;
        if (vtv > 1e-300) {
            double tau = 2.0/vtv;
            for (int c=j;c<7;c++){
                double s=0.0; for (int i=j;i<15;i++) s += v[i]*M[i][c];
                s *= tau;
                for (int i=j;i<15;i++) M[i][c] -= s*v[i];
            }
            for (int c=0;c<7;c++){
                double s=0.0; for (int i=j;i<15;i++) s += v[i]*T[i][c];
                s *= tau;
                for (int i=j;i<15;i++) T[i][c] -= s*v[i];
            }
        }
        M[j][j] = alpha;
        for (int i=j+1;i<15;i++) M[i][j]=0.0;
    }
    double btd[49];
    for (int c=0;c<7;c++){
        double xs[7];
        for (int i=6;i>=0;i--){
            double s = T[i][c];
            for (int k2=i+1;k2<7;k2++) s -= M[i][k2]*xs[k2];
            xs[i] = s / M[i][i];
        }
        for (int i=0;i<7;i++) btd[i*7+c] = xs[i];
    }
    for (int i=0;i<49;i++) ka->bt[i] = (float)btd[i];
    double mb = 0.0;
    for (int v=0;v<7;v++){
        double rs = 0.0;
        for (int c=0;c<7;c++) rs += fabs(btd[v*7+c]);
        if (rs > mb) mb = rs;
    }
    *dual = (mb * 128.0 > 8192.0);
    for (int v=0;v<7;v++){
        float s = ka->bt[v*7+0];
        for (int w=1;w<7;w++) s = s + ka->bt[v*7+w];
        ka->einit[v] = -128.f * s;
    }
}

// ---------------- Kernel: weight transform -> per-(step,ng12) 1KB frag layout ----------------
__global__ void wt16_kernel(const float* __restrict__ w, _Float16* __restrict__ W3) {
    int idx = blockIdx.x*256 + threadIdx.x;     // chunk id, < 7*6*12*64 = 32256
    if (idx >= 32256) return;
    const int lane = idx & 63;
    int t = idx >> 6;
    const int ng = t % 12; t /= 12;
    const int step = t % 6; t /= 6;
    const int v = t;
    const int l15 = lane & 15, g = lane >> 4;
    const int rr = step >> 1, ch = step & 1;
    const int o = ng*16 + l15;
    const float Gf[7][3] = {{1,0,0},{1,1,1},{1,-1,1},{1,2,4},{1,-2,4},{1,3,9},{0,0,1}};
    const float g0 = Gf[v][0], g1 = Gf[v][1], g2 = Gf[v][2];
    f16x8 outv;
    #pragma unroll
    for (int e = 0; e < 8; ++e) {
        const int c = ch*32 + g*8 + e;
        const float* wp = w + (((size_t)o*CIN + c)*3 + rr)*3;
        float val = wp[0]*g0 + wp[1]*g1 + wp[2]*g2;
        val = rintf(val);
        val = fminf(fmaxf(val, -32768.f), 32767.f);
        outv[e] = (_Float16)val;
    }
    *(f16x8*)(W3 + (size_t)idx*8) = outv;
}

// ---------------- Main kernel (MODE-ablatable) ----------------
// MODE 0: full.  1: no GEMM.  2: GEMM only (no staging/E).  3: epilogue only.
// 6: full minus final out-store (LDS consumed via asm).

#define BLOAD(S, sl) do { \
    br[sl] = *(const f16x8*)(W + (size_t)((S)*12 + ng)*512 + lane*8); \
} while (0)

template<bool DUAL, int MODE>
__global__ __launch_bounds__(768, 3)
void main_kernel(const float* __restrict__ x, const _Float16* __restrict__ W,
                 const KArgs ka,
                 const float* __restrict__ alpha, const float* __restrict__ beta,
                 const float* __restrict__ sfp, const float* __restrict__ sop,
                 float* __restrict__ out)
{
    constexpr bool DO_STAGE = (MODE==0 || MODE==1 || MODE==6);
    constexpr bool DO_GEMM  = (MODE==0 || MODE==2 || MODE==6);
    constexpr bool DO_STORE = (MODE!=6);

    extern __shared__ char lds[];
    constexpr int EHOFF = 0;
    constexpr int ELOFF = 64512;
    constexpr int RAWOFF = 0;
    constexpr int RAWSTR = 68;

    const int kq = blockIdx.x, n = blockIdx.y, k0 = kq*KR;
    const int tid = threadIdx.x;
    const int wid = tid >> 6, lane = tid & 63, l15 = lane & 15, g = lane >> 4;
    const int ng = wid;
    const int t_e = wid, cc = lane;

    f16x8 br[6];
    if constexpr (DO_GEMM) {
        BLOAD(0, 0); BLOAD(1, 1); BLOAD(2, 2); BLOAD(3, 3); BLOAD(4, 4); BLOAD(5, 5);
    }

    if constexpr (DO_STAGE) {
        // ---- stage raw x rows (k0-1 .. k0+4) as biased u8, stride 68 ----
        #pragma unroll
        for (int j = 0; j < 7; ++j) {
            int idx = j*768 + tid;
            int row = idx / 14, w = idx - row*14;
            int krow = row >> 6;
            int ch = row & 63;
            int xr = k0 + krow - 1;
            u32 bword = 0x80808080u;
            if (xr >= 0 && xr < HWD) {
                const float4 vx = *(const float4*)(x + (((size_t)(n*CIN + ch))*HWD + xr)*HWD + w*4);
                bword = (u32)(int)(vx.x + 128.f) | ((u32)(int)(vx.y + 128.f) << 8)
                      | ((u32)(int)(vx.z + 128.f) << 16) | ((u32)(int)(vx.w + 128.f) << 24);
            }
            *(u32*)(lds + RAWOFF + row*RAWSTR + 4 + w*4) = bword;
        }
        #pragma unroll
        for (int jj = 0; jj < 2; ++jj) {
            int p = jj*768 + tid;
            if (p < 1152) {
                int row = p/3, ws = p - row*3;
                int wb = (ws == 0) ? 0 : (56 + ws*4);
                *(u32*)(lds + RAWOFF + row*RAWSTR + wb) = 0x80808080u;
            }
        }
        WAITL(); SBAR();

        // ---- extract per-thread x window into 12 packed u32 regs ----
        u32 xwL[6], xwH[6];
        {
            const int a0 = (5*t_e + 3) & ~7;
            const int sh = ((5*t_e + 3) & 7) * 8;
            #pragma unroll
            for (int krow = 0; krow < 6; ++krow) {
                const char* pb = lds + RAWOFF + (krow*64 + cc)*RAWSTR + a0;
                u64 lo = *(const u64*)pb;
                u64 hi = *(const u64*)(pb + 8);
                u64 wnd = (lo >> sh) | ((hi << 1) << (63 - sh));
                xwL[krow] = (u32)wnd;
                xwH[krow] = (u32)(wnd >> 32);
            }
        }
        WAITL(); SBAR();

        // ---- build the FULL E table (all 7 v) ----
        #pragma unroll 1
        for (int v = 0; v < 7; ++v) {
            const float b0 = ka.bt[v*7+0], b1 = ka.bt[v*7+1], b2 = ka.bt[v*7+2];
            const float b3 = ka.bt[v*7+3], b4 = ka.bt[v*7+4], b5 = ka.bt[v*7+5], b6 = ka.bt[v*7+6];
            const float einit = ka.einit[v];
            #pragma unroll
            for (int krow = 0; krow < 6; ++krow) {
                const u32 Aw = xwL[krow], Bw = xwH[krow];
                float e = einit;
                e = fmaf(b0, (float)(Aw & 255u),         e);
                e = fmaf(b1, (float)((Aw >> 8) & 255u),  e);
                e = fmaf(b2, (float)((Aw >> 16) & 255u), e);
                e = fmaf(b3, (float)(Aw >> 24),          e);
                e = fmaf(b4, (float)(Bw & 255u),         e);
                e = fmaf(b5, (float)((Bw >> 8) & 255u),  e);
                e = fmaf(b6, (float)((Bw >> 16) & 255u), e);
                e = rintf(e);
                e = fminf(fmaxf(e, -32768.f), 32767.f);
                const int row = krow*12 + t_e;
                const int sb = v*9216 + row*128 + ((((cc >> 3) ^ (row & 7)) << 4) | ((cc & 7) << 1));
                if (DUAL) {
                    float ehs = rintf(e * (1.f/2048.f)) * 2048.f;
                    *(_Float16*)(lds + EHOFF + sb) = (_Float16)ehs;
                    *(_Float16*)(lds + ELOFF + sb) = (_Float16)(e - ehs);
                } else {
                    *(_Float16*)(lds + EHOFF + sb) = (_Float16)e;
                }
            }
        }
        WAITL(); SBAR();
    } else {
        SBAR();
    }

    // ---- accumulators ----
    f32x4 yu[5][3], mv[3];
    #pragma unroll
    for (int u = 0; u < 5; ++u)
        #pragma unroll
        for (int f = 0; f < 3; ++f) yu[u][f] = f32x4{0.f,0.f,0.f,0.f};
    #pragma unroll
    for (int f = 0; f < 3; ++f) mv[f] = f32x4{0.f,0.f,0.f,0.f};

    if constexpr (DO_GEMM) {
        #pragma unroll 1
        for (int v = 0; v < 7; ++v) {
            #pragma unroll
            for (int si = 0; si < 6; ++si) {
                const int rr = si >> 1, chh = si & 1;
                f16x8 a0f, a1f, a2f;
                {
                    const int r0 = rr*12 +  0 + l15;
                    const int r1 = rr*12 + 16 + l15;
                    const int r2 = rr*12 + 32 + l15;
                    a0f = *(const f16x8*)(lds + EHOFF + v*9216 + r0*128 + ((((chh << 2) | g) ^ (r0 & 7)) << 4));
                    a1f = *(const f16x8*)(lds + EHOFF + v*9216 + r1*128 + ((((chh << 2) | g) ^ (r1 & 7)) << 4));
                    a2f = *(const f16x8*)(lds + EHOFF + v*9216 + r2*128 + ((((chh << 2) | g) ^ (r2 & 7)) << 4));
                }
                mv[0] = __builtin_amdgcn_mfma_f32_16x16x32_f16(a0f, br[si], mv[0], 0,0,0);
                mv[1] = __builtin_amdgcn_mfma_f32_16x16x32_f16(a1f, br[si], mv[1], 0,0,0);
                mv[2] = __builtin_amdgcn_mfma_f32_16x16x32_f16(a2f, br[si], mv[2], 0,0,0);
                if (DUAL) {
                    const int r0 = rr*12 +  0 + l15;
                    const int r1 = rr*12 + 16 + l15;
                    const int r2 = rr*12 + 32 + l15;
                    f16x8 l0 = *(const f16x8*)(lds + ELOFF + v*9216 + r0*128 + ((((chh << 2) | g) ^ (r0 & 7)) << 4));
                    f16x8 l1 = *(const f16x8*)(lds + ELOFF + v*9216 + r1*128 + ((((chh << 2) | g) ^ (r1 & 7)) << 4));
                    f16x8 l2 = *(const f16x8*)(lds + ELOFF + v*9216 + r2*128 + ((((chh << 2) | g) ^ (r2 & 7)) << 4));
                    mv[0] = __builtin_amdgcn_mfma_f32_16x16x32_f16(l0, br[si], mv[0], 0,0,0);
                    mv[1] = __builtin_amdgcn_mfma_f32_16x16x32_f16(l1, br[si], mv[1], 0,0,0);
                    mv[2] = __builtin_amdgcn_mfma_f32_16x16x32_f16(l2, br[si], mv[2], 0,0,0);
                }
                if (v < 6) BLOAD((v+1)*6 + si, si);
            }
            {
                const float a0c = ATT[v][0], a1c = ATT[v][1], a2c = ATT[v][2];
                const float a3c = ATT[v][3], a4c = ATT[v][4];
                #pragma unroll
                for (int f = 0; f < 3; ++f) {
                    yu[0][f] += a0c * mv[f];
                    yu[1][f] += a1c * mv[f];
                    yu[2][f] += a2c * mv[f];
                    yu[3][f] += a3c * mv[f];
                    yu[4][f] += a4c * mv[f];
                    mv[f] = f32x4{0.f,0.f,0.f,0.f};
                }
            }
        }
    }

    SBAR();   // LDS reusable for epilogue

    // ---- epilogue: quantize to u8 in LDS, then coalesced aligned output pass ----
    const float rdenom = 1.f / (120.f * sfp[0]);
    const int o = ng*16 + l15;
    const float avv = alpha[o];
    const float bev = rintf(beta[o] * sop[0]);
    unsigned char* ldsb = (unsigned char*)lds;    // [192][224]
    #pragma unroll
    for (int af = 0; af < 3; ++af) {
        #pragma unroll
        for (int q = 0; q < 4; ++q) {
            const int m = af*16 + g*4 + q;
            const int kl = m / 12, t = m - kl*12;
            #pragma unroll
            for (int u = 0; u < 5; ++u) {
                const int col = t*5 + u;
                if (col < HWD) {
                    float yv = yu[u][af][q];
                    yv = rintf(yv * rdenom);
                    yv = rintf(avv*yv) + bev;
                    yv = rintf(yv);
                    yv = fminf(fmaxf(yv, -128.f), 127.f);
                    yv = fmaxf(yv, 0.f);
                    ldsb[o*224 + kl*56 + col] = (unsigned char)(int)yv;
                }
            }
        }
    }
    WAITL(); SBAR();
    float* ob = out + ((size_t)(n*COUT))*3136 + k0*56;
    #pragma unroll
    for (int it = 0; it < 14; ++it) {
        int i = it*768 + tid;
        int o2 = i / 56, q4 = i - o2*56;
        u32 wb2 = *(const u32*)(ldsb + o2*224 + q4*4);
        if constexpr (DO_STORE) {
            float4 f;
            f.x = (float)(wb2 & 255u);
            f.y = (float)((wb2 >> 8) & 255u);
            f.z = (float)((wb2 >> 16) & 255u);
            f.w = (float)(wb2 >> 24);
            *(float4*)(ob + (size_t)o2*3136 + q4*4) = f;
        } else {
            asm volatile("" :: "v"(wb2));   // consume; no global store
        }
    }
}

extern "C" void kernel_launch(void* const* d_in, const int* in_sizes, int n_in,
                              void* d_out, int out_size, void* d_ws, size_t ws_size,
                              hipStream_t stream) {
    const float* x      = (const float*)d_in[0];
    const float* weight = (const float*)d_in[1];
    const float* alpha  = (const float*)d_in[2];
    const float* beta   = (const float*)d_in[3];
    const float* sf     = (const float*)d_in[4];
    const float* so     = (const float*)d_in[5];
    float* out = (float*)d_out;

    _Float16* Wp = (_Float16*)((char*)d_ws + WS_W_OFF);

    KArgs ka;
    bool dual;
    host_compute_bt(&ka, &dual);

    wt16_kernel<<<(32256 + 255)/256, 256, 0, stream>>>(weight, Wp);

    dim3 grid(NKQ, NBATCH);
    if (dual) {
        (void)hipFuncSetAttribute((const void*)&main_kernel<true,0>,
                                  hipFuncAttributeMaxDynamicSharedMemorySize, 129024);
        main_kernel<true,0><<<grid, 768, 129024, stream>>>(x, Wp, ka, alpha, beta, sf, so, out);
    } else {
        (void)hipFuncSetAttribute((const void*)&main_kernel<false,1>,
                                  hipFuncAttributeMaxDynamicSharedMemorySize, 64512);
        (void)hipFuncSetAttribute((const void*)&main_kernel<false,2>,
                                  hipFuncAttributeMaxDynamicSharedMemorySize, 64512);
        (void)hipFuncSetAttribute((const void*)&main_kernel<false,6>,
                                  hipFuncAttributeMaxDynamicSharedMemorySize, 64512);
        (void)hipFuncSetAttribute((const void*)&main_kernel<false,3>,
                                  hipFuncAttributeMaxDynamicSharedMemorySize, 64512);
        (void)hipFuncSetAttribute((const void*)&main_kernel<false,0>,
                                  hipFuncAttributeMaxDynamicSharedMemorySize, 64512);
        // Diagnostics (write garbage into d_out; harmless — MODE 0 rewrites it last).
        main_kernel<false,1><<<grid, 768, 64512, stream>>>(x, Wp, ka, alpha, beta, sf, so, out);
        main_kernel<false,2><<<grid, 768, 64512, stream>>>(x, Wp, ka, alpha, beta, sf, so, out);
        main_kernel<false,6><<<grid, 768, 64512, stream>>>(x, Wp, ka, alpha, beta, sf, so, out);
        main_kernel<false,3><<<grid, 768, 64512, stream>>>(x, Wp, ka, alpha, beta, sf, so, out);
        // Real kernel LAST: d_out ends correct and deterministic.
        main_kernel<false,0><<<grid, 768, 64512, stream>>>(x, Wp, ka, alpha, beta, sf, so, out);
    }
}

// Round 16
// 81.700 us; speedup vs baseline: 2.3076x; 2.3076x over previous
//
#include <hip/hip_runtime.h>
#include <math.h>

typedef _Float16 f16x8 __attribute__((ext_vector_type(8)));
typedef float f32x4 __attribute__((ext_vector_type(4)));
typedef unsigned int u32;
typedef unsigned long long u64;

#define NBATCH 32
#define CIN    64
#define COUT   192
#define HWD    56
#define KR     4
#define NKQ    14

#define WS_W_OFF  1024

#define SBAR()  do { __builtin_amdgcn_s_barrier(); asm volatile("" ::: "memory"); } while(0)
#define WAITL() asm volatile("s_waitcnt lgkmcnt(0)" ::: "memory")

struct KArgs {
    float bt[49];
    float einit[7];
};

// AT transposed: ATT[v][u] = AT[u][v]
__device__ const float ATT[7][5] = {
    {1,0,0,0,0},{1,1,1,1,1},{1,-1,1,-1,1},{1,2,4,8,16},{1,-2,4,-8,16},{1,3,9,27,81},{0,0,0,0,1}};

// ---------------- Host: Householder QR lstsq for BT (f64) + range flag ----------------
static void host_compute_bt(KArgs* ka, bool* dual) {
    const double ATd[5][7] = {
        {1,1,1,1,1,1,0},{0,1,-1,2,-2,3,0},{0,1,1,4,4,9,0},{0,1,-1,8,-8,27,0},{0,1,1,16,16,81,1}};
    const double pts[6] = {0.0,1.0,-1.0,2.0,-2.0,3.0};
    double G[7][3];
    for (int i=0;i<6;i++){ G[i][0]=1.0; G[i][1]=pts[i]; G[i][2]=pts[i]*pts[i]; }
    G[6][0]=0.0; G[6][1]=0.0; G[6][2]=1.0;
    double M[15][7], T[15][7];
    for (int p=0;p<3;p++)
        for (int u=0;u<5;u++)
            for (int v=0;v<7;v++)
                M[5*p+u][v] = ATd[u][v]*G[v][p];
    for (int i=0;i<15;i++) for (int j=0;j<7;j++) T[i][j]=0.0;
    for (int p=0;p<3;p++) for (int kk=0;kk<5;kk++) T[5*p+kk][kk+p]=1.0;
    for (int j=0;j<7;j++){
        double sig=0.0; for (int i=j;i<15;i++) sig += M[i][j]*M[i][j];
        double nrm = sqrt(sig);
        double ajj = M[j][j];
        double alpha = (ajj > 0.0) ? -nrm : nrm;
        double v[15];
        v[j] = ajj - alpha;
        for (int i=j+1;i<15;i++) v[i] = M[i][j];
        double vtv = sig - 2.0*alpha*ajj + alpha*alpha;
        if (vtv > 1e-300) {
            double tau = 2.0/vtv;
            for (int c=j;c<7;c++){
                double s=0.0; for (int i=j;i<15;i++) s += v[i]*M[i][c];
                s *= tau;
                for (int i=j;i<15;i++) M[i][c] -= s*v[i];
            }
            for (int c=0;c<7;c++){
                double s=0.0; for (int i=j;i<15;i++) s += v[i]*T[i][c];
                s *= tau;
                for (int i=j;i<15;i++) T[i][c] -= s*v[i];
            }
        }
        M[j][j] = alpha;
        for (int i=j+1;i<15;i++) M[i][j]=0.0;
    }
    double btd[49];
    for (int c=0;c<7;c++){
        double xs[7];
        for (int i=6;i>=0;i--){
            double s = T[i][c];
            for (int k2=i+1;k2<7;k2++) s -= M[i][k2]*xs[k2];
            xs[i] = s / M[i][i];
        }
        for (int i=0;i<7;i++) btd[i*7+c] = xs[i];
    }
    for (int i=0;i<49;i++) ka->bt[i] = (float)btd[i];
    double mb = 0.0;
    for (int v=0;v<7;v++){
        double rs = 0.0;
        for (int c=0;c<7;c++) rs += fabs(btd[v*7+c]);
        if (rs > mb) mb = rs;
    }
    *dual = (mb * 128.0 > 8192.0);
    for (int v=0;v<7;v++){
        float s = ka->bt[v*7+0];
        for (int w=1;w<7;w++) s = s + ka->bt[v*7+w];
        ka->einit[v] = -128.f * s;
    }
}

// ---------------- Kernel: weight transform -> per-(step,ng12) 1KB frag layout ----------------
__global__ void wt16_kernel(const float* __restrict__ w, _Float16* __restrict__ W3) {
    int idx = blockIdx.x*256 + threadIdx.x;     // chunk id, < 7*6*12*64 = 32256
    if (idx >= 32256) return;
    const int lane = idx & 63;
    int t = idx >> 6;
    const int ng = t % 12; t /= 12;
    const int step = t % 6; t /= 6;
    const int v = t;
    const int l15 = lane & 15, g = lane >> 4;
    const int rr = step >> 1, ch = step & 1;
    const int o = ng*16 + l15;
    const float Gf[7][3] = {{1,0,0},{1,1,1},{1,-1,1},{1,2,4},{1,-2,4},{1,3,9},{0,0,1}};
    const float g0 = Gf[v][0], g1 = Gf[v][1], g2 = Gf[v][2];
    f16x8 outv;
    #pragma unroll
    for (int e = 0; e < 8; ++e) {
        const int c = ch*32 + g*8 + e;
        const float* wp = w + (((size_t)o*CIN + c)*3 + rr)*3;
        float val = wp[0]*g0 + wp[1]*g1 + wp[2]*g2;
        val = rintf(val);
        val = fminf(fmaxf(val, -32768.f), 32767.f);
        outv[e] = (_Float16)val;
    }
    *(f16x8*)(W3 + (size_t)idx*8) = outv;
}

// ---------------- Main kernel: v-pipelined (GEMM(v) || E-build(v+1)), 2-plane ping-pong ----------------

#define BLOAD(S, sl) do { \
    br[sl] = *(const f16x8*)(W + (size_t)((S)*12 + ng)*512 + lane*8); \
} while (0)

template<bool DUAL>
__global__ __launch_bounds__(768, 3)
void main_kernel(const float* __restrict__ x, const _Float16* __restrict__ W,
                 const KArgs ka,
                 const float* __restrict__ alpha, const float* __restrict__ beta,
                 const float* __restrict__ sfp, const float* __restrict__ sop,
                 float* __restrict__ out)
{
    constexpr int PEH0   = 0;                       // E-hi plane 0 (9216 B)
    constexpr int PEH1   = 9216;                    // E-hi plane 1
    constexpr int PEL0   = DUAL ? 18432 : 0;        // E-lo planes (dual only)
    constexpr int PEL1   = DUAL ? 27648 : 0;
    constexpr int RAWOFF = DUAL ? 36864 : 18432;    // raw x (26112 B, persists)
    constexpr int LDSSZ  = DUAL ? 62976 : 44544;
    constexpr int RAWSTR = 68;
    __shared__ char lds[LDSSZ];

    const int kq = blockIdx.x, n = blockIdx.y, k0 = kq*KR;
    const int tid = threadIdx.x;
    const int wid = tid >> 6, lane = tid & 63, l15 = lane & 15, g = lane >> 4;
    const int ng = wid;
    const int t_e = wid, cc = lane;

    // ---- B register ring (depth 6): issue ASAP ----
    f16x8 br[6];
    BLOAD(0, 0); BLOAD(1, 1); BLOAD(2, 2); BLOAD(3, 3); BLOAD(4, 4); BLOAD(5, 5);

    // ---- stage raw x rows (k0-1 .. k0+4) as biased u8, stride 68 ----
    #pragma unroll
    for (int j = 0; j < 7; ++j) {
        int idx = j*768 + tid;                   // < 5376 data words
        int row = idx / 14, w = idx - row*14;
        int krow = row >> 6;
        int ch = row & 63;
        int xr = k0 + krow - 1;
        u32 bword = 0x80808080u;
        if (xr >= 0 && xr < HWD) {
            const float4 vx = *(const float4*)(x + (((size_t)(n*CIN + ch))*HWD + xr)*HWD + w*4);
            bword = (u32)(int)(vx.x + 128.f) | ((u32)(int)(vx.y + 128.f) << 8)
                  | ((u32)(int)(vx.z + 128.f) << 16) | ((u32)(int)(vx.w + 128.f) << 24);
        }
        *(u32*)(lds + RAWOFF + row*RAWSTR + 4 + w*4) = bword;
    }
    #pragma unroll
    for (int jj = 0; jj < 2; ++jj) {             // pads: bytes 0..3, 60..67
        int p = jj*768 + tid;
        if (p < 1152) {
            int row = p/3, ws = p - row*3;
            int wb = (ws == 0) ? 0 : (56 + ws*4);
            *(u32*)(lds + RAWOFF + row*RAWSTR + wb) = 0x80808080u;
        }
    }
    WAITL(); SBAR();

    // ---- extract per-thread x window (t = wid, c = lane) into 12 packed u32 regs ----
    u32 xwL[6], xwH[6];
    {
        const int a0 = (5*t_e + 3) & ~7;
        const int sh = ((5*t_e + 3) & 7) * 8;
        #pragma unroll
        for (int krow = 0; krow < 6; ++krow) {
            const char* pb = lds + RAWOFF + (krow*64 + cc)*RAWSTR + a0;
            u64 lo = *(const u64*)pb;
            u64 hi = *(const u64*)(pb + 8);
            u64 wnd = (lo >> sh) | ((hi << 1) << (63 - sh));
            xwL[krow] = (u32)wnd;
            xwH[krow] = (u32)(wnd >> 32);
        }
    }

    // ---- E-build for v=0 into plane 0 ----
    {
        const float b0 = ka.bt[0], b1 = ka.bt[1], b2 = ka.bt[2], b3 = ka.bt[3];
        const float b4 = ka.bt[4], b5 = ka.bt[5], b6 = ka.bt[6];
        const float einit = ka.einit[0];
        #pragma unroll
        for (int krow = 0; krow < 6; ++krow) {
            const u32 Aw = xwL[krow], Bw = xwH[krow];
            float e = einit;
            e = fmaf(b0, (float)(Aw & 255u),         e);
            e = fmaf(b1, (float)((Aw >> 8) & 255u),  e);
            e = fmaf(b2, (float)((Aw >> 16) & 255u), e);
            e = fmaf(b3, (float)(Aw >> 24),          e);
            e = fmaf(b4, (float)(Bw & 255u),         e);
            e = fmaf(b5, (float)((Bw >> 8) & 255u),  e);
            e = fmaf(b6, (float)((Bw >> 16) & 255u), e);
            e = rintf(e);
            e = fminf(fmaxf(e, -32768.f), 32767.f);
            const int row = krow*12 + t_e;
            const int sb = row*128 + ((((cc >> 3) ^ (row & 7)) << 4) | ((cc & 7) << 1));
            if (DUAL) {
                float ehs = rintf(e * (1.f/2048.f)) * 2048.f;
                *(_Float16*)(lds + PEH0 + sb) = (_Float16)ehs;
                *(_Float16*)(lds + PEL0 + sb) = (_Float16)(e - ehs);
            } else {
                *(_Float16*)(lds + PEH0 + sb) = (_Float16)e;
            }
        }
    }
    WAITL(); SBAR();    // plane 0 published

    // ---- accumulators ----
    f32x4 yu[5][3], mv[3];
    #pragma unroll
    for (int u = 0; u < 5; ++u)
        #pragma unroll
        for (int f = 0; f < 3; ++f) yu[u][f] = f32x4{0.f,0.f,0.f,0.f};
    #pragma unroll
    for (int f = 0; f < 3; ++f) mv[f] = f32x4{0.f,0.f,0.f,0.f};

    // ---- pipelined main loop: GEMM(v) from plane[v&1]  ||  E-build(v+1) -> plane[(v+1)&1] ----
    #pragma unroll 1
    for (int v = 0; v < 7; ++v) {
        const int rEH = (v & 1) ? PEH1 : PEH0;
        const int rEL = (v & 1) ? PEL1 : PEL0;
        const int wEH = (v & 1) ? PEH0 : PEH1;
        const int wEL = (v & 1) ? PEL0 : PEL1;
        // next-v E coefficients (hoisted; dead for v==6)
        float nb0=0.f,nb1=0.f,nb2=0.f,nb3=0.f,nb4=0.f,nb5=0.f,nb6=0.f,nei=0.f;
        if (v < 6) {
            nb0 = ka.bt[(v+1)*7+0]; nb1 = ka.bt[(v+1)*7+1]; nb2 = ka.bt[(v+1)*7+2];
            nb3 = ka.bt[(v+1)*7+3]; nb4 = ka.bt[(v+1)*7+4]; nb5 = ka.bt[(v+1)*7+5];
            nb6 = ka.bt[(v+1)*7+6]; nei = ka.einit[v+1];
        }
        #pragma unroll
        for (int si = 0; si < 6; ++si) {
            const int rr = si >> 1, chh = si & 1;
            // --- GEMM step si ---
            f16x8 a0f, a1f, a2f;
            {
                const int r0 = rr*12 +  0 + l15;
                const int r1 = rr*12 + 16 + l15;
                const int r2 = rr*12 + 32 + l15;
                a0f = *(const f16x8*)(lds + rEH + r0*128 + ((((chh << 2) | g) ^ (r0 & 7)) << 4));
                a1f = *(const f16x8*)(lds + rEH + r1*128 + ((((chh << 2) | g) ^ (r1 & 7)) << 4));
                a2f = *(const f16x8*)(lds + rEH + r2*128 + ((((chh << 2) | g) ^ (r2 & 7)) << 4));
            }
            mv[0] = __builtin_amdgcn_mfma_f32_16x16x32_f16(a0f, br[si], mv[0], 0,0,0);
            mv[1] = __builtin_amdgcn_mfma_f32_16x16x32_f16(a1f, br[si], mv[1], 0,0,0);
            mv[2] = __builtin_amdgcn_mfma_f32_16x16x32_f16(a2f, br[si], mv[2], 0,0,0);
            if (DUAL) {
                const int r0 = rr*12 +  0 + l15;
                const int r1 = rr*12 + 16 + l15;
                const int r2 = rr*12 + 32 + l15;
                f16x8 l0 = *(const f16x8*)(lds + rEL + r0*128 + ((((chh << 2) | g) ^ (r0 & 7)) << 4));
                f16x8 l1 = *(const f16x8*)(lds + rEL + r1*128 + ((((chh << 2) | g) ^ (r1 & 7)) << 4));
                f16x8 l2 = *(const f16x8*)(lds + rEL + r2*128 + ((((chh << 2) | g) ^ (r2 & 7)) << 4));
                mv[0] = __builtin_amdgcn_mfma_f32_16x16x32_f16(l0, br[si], mv[0], 0,0,0);
                mv[1] = __builtin_amdgcn_mfma_f32_16x16x32_f16(l1, br[si], mv[1], 0,0,0);
                mv[2] = __builtin_amdgcn_mfma_f32_16x16x32_f16(l2, br[si], mv[2], 0,0,0);
            }
            // --- E-build krow si of v+1 (VALU; overlaps MFMA pipe) ---
            if (v < 6) {
                const u32 Aw = xwL[si], Bw = xwH[si];
                float e = nei;
                e = fmaf(nb0, (float)(Aw & 255u),         e);
                e = fmaf(nb1, (float)((Aw >> 8) & 255u),  e);
                e = fmaf(nb2, (float)((Aw >> 16) & 255u), e);
                e = fmaf(nb3, (float)(Aw >> 24),          e);
                e = fmaf(nb4, (float)(Bw & 255u),         e);
                e = fmaf(nb5, (float)((Bw >> 8) & 255u),  e);
                e = fmaf(nb6, (float)((Bw >> 16) & 255u), e);
                e = rintf(e);
                e = fminf(fmaxf(e, -32768.f), 32767.f);
                const int row = si*12 + t_e;
                const int sb = row*128 + ((((cc >> 3) ^ (row & 7)) << 4) | ((cc & 7) << 1));
                if (DUAL) {
                    float ehs = rintf(e * (1.f/2048.f)) * 2048.f;
                    *(_Float16*)(lds + wEH + sb) = (_Float16)ehs;
                    *(_Float16*)(lds + wEL + sb) = (_Float16)(e - ehs);
                } else {
                    *(_Float16*)(lds + wEH + sb) = (_Float16)e;
                }
            }
            // --- refill B slot si with step (v+1, si) ---
            if (v < 6) BLOAD((v+1)*6 + si, si);
        }
        // FOLD(v): yu += ATT[v][u] * mv
        {
            const float a0c = ATT[v][0], a1c = ATT[v][1], a2c = ATT[v][2];
            const float a3c = ATT[v][3], a4c = ATT[v][4];
            #pragma unroll
            for (int f = 0; f < 3; ++f) {
                yu[0][f] += a0c * mv[f];
                yu[1][f] += a1c * mv[f];
                yu[2][f] += a2c * mv[f];
                yu[3][f] += a3c * mv[f];
                yu[4][f] += a4c * mv[f];
                mv[f] = f32x4{0.f,0.f,0.f,0.f};
            }
        }
        WAITL(); SBAR();   // my reads of plane[v&1] and writes of plane[(v+1)&1] done
    }

    // ---- epilogue: quantize to u8 in LDS (overlays planes+RAW), coalesced output ----
    const float rdenom = 1.f / (120.f * sfp[0]);
    const int o = ng*16 + l15;
    const float avv = alpha[o];
    const float bev = rintf(beta[o] * sop[0]);
    unsigned char* ldsb = (unsigned char*)lds;    // [192][224] = 43008 B
    #pragma unroll
    for (int af = 0; af < 3; ++af) {
        #pragma unroll
        for (int q = 0; q < 4; ++q) {
            const int m = af*16 + g*4 + q;
            const int kl = m / 12, t = m - kl*12;
            #pragma unroll
            for (int u = 0; u < 5; ++u) {
                const int col = t*5 + u;
                if (col < HWD) {
                    float yv = yu[u][af][q];
                    yv = rintf(yv * rdenom);
                    yv = rintf(avv*yv) + bev;
                    yv = rintf(yv);
                    yv = fminf(fmaxf(yv, -128.f), 127.f);
                    yv = fmaxf(yv, 0.f);
                    ldsb[o*224 + kl*56 + col] = (unsigned char)(int)yv;
                }
            }
        }
    }
    WAITL(); SBAR();
    float* ob = out + ((size_t)(n*COUT))*3136 + k0*56;
    #pragma unroll
    for (int it = 0; it < 14; ++it) {
        int i = it*768 + tid;
        int o2 = i / 56, q4 = i - o2*56;
        u32 wb2 = *(const u32*)(ldsb + o2*224 + q4*4);
        float4 f;
        f.x = (float)(wb2 & 255u);
        f.y = (float)((wb2 >> 8) & 255u);
        f.z = (float)((wb2 >> 16) & 255u);
        f.w = (float)(wb2 >> 24);
        *(float4*)(ob + (size_t)o2*3136 + q4*4) = f;
    }
}

extern "C" void kernel_launch(void* const* d_in, const int* in_sizes, int n_in,
                              void* d_out, int out_size, void* d_ws, size_t ws_size,
                              hipStream_t stream) {
    const float* x      = (const float*)d_in[0];
    const float* weight = (const float*)d_in[1];
    const float* alpha  = (const float*)d_in[2];
    const float* beta   = (const float*)d_in[3];
    const float* sf     = (const float*)d_in[4];
    const float* so     = (const float*)d_in[5];
    float* out = (float*)d_out;

    _Float16* Wp = (_Float16*)((char*)d_ws + WS_W_OFF);

    KArgs ka;
    bool dual;
    host_compute_bt(&ka, &dual);

    wt16_kernel<<<(32256 + 255)/256, 256, 0, stream>>>(weight, Wp);

    dim3 grid(NKQ, NBATCH);
    if (dual) {
        main_kernel<true><<<grid, 768, 0, stream>>>(x, Wp, ka, alpha, beta, sf, so, out);
    } else {
        main_kernel<false><<<grid, 768, 0, stream>>>(x, Wp, ka, alpha, beta, sf, so, out);
    }
}

// Round 17
// 65.447 us; speedup vs baseline: 2.8806x; 1.2483x over previous
//
#include <hip/hip_runtime.h>
#include <math.h>

typedef _Float16 f16x8 __attribute__((ext_vector_type(8)));
typedef float f32x4 __attribute__((ext_vector_type(4)));
typedef unsigned int u32;
typedef unsigned long long u64;

#define NBATCH 32
#define CIN    64
#define COUT   192
#define HWD    56
#define KR     4
#define NKQ    14

#define WS_W_OFF  1024

#define SBAR()  do { __builtin_amdgcn_s_barrier(); asm volatile("" ::: "memory"); } while(0)
#define WAITL() asm volatile("s_waitcnt lgkmcnt(0)" ::: "memory")

struct KArgs {
    float bt[49];
    float einit[7];
};

// AT transposed: ATT[v][u] = AT[u][v]
__device__ const float ATT[7][5] = {
    {1,0,0,0,0},{1,1,1,1,1},{1,-1,1,-1,1},{1,2,4,8,16},{1,-2,4,-8,16},{1,3,9,27,81},{0,0,0,0,1}};

// ---------------- Host: Householder QR lstsq for BT (f64) + range flag ----------------
static void host_compute_bt(KArgs* ka, bool* dual) {
    const double ATd[5][7] = {
        {1,1,1,1,1,1,0},{0,1,-1,2,-2,3,0},{0,1,1,4,4,9,0},{0,1,-1,8,-8,27,0},{0,1,1,16,16,81,1}};
    const double pts[6] = {0.0,1.0,-1.0,2.0,-2.0,3.0};
    double G[7][3];
    for (int i=0;i<6;i++){ G[i][0]=1.0; G[i][1]=pts[i]; G[i][2]=pts[i]*pts[i]; }
    G[6][0]=0.0; G[6][1]=0.0; G[6][2]=1.0;
    double M[15][7], T[15][7];
    for (int p=0;p<3;p++)
        for (int u=0;u<5;u++)
            for (int v=0;v<7;v++)
                M[5*p+u][v] = ATd[u][v]*G[v][p];
    for (int i=0;i<15;i++) for (int j=0;j<7;j++) T[i][j]=0.0;
    for (int p=0;p<3;p++) for (int kk=0;kk<5;kk++) T[5*p+kk][kk+p]=1.0;
    for (int j=0;j<7;j++){
        double sig=0.0; for (int i=j;i<15;i++) sig += M[i][j]*M[i][j];
        double nrm = sqrt(sig);
        double ajj = M[j][j];
        double alpha = (ajj > 0.0) ? -nrm : nrm;
        double v[15];
        v[j] = ajj - alpha;
        for (int i=j+1;i<15;i++) v[i] = M[i][j];
        double vtv = sig - 2.0*alpha*ajj + alpha*alpha;
        if (vtv > 1e-300) {
            double tau = 2.0/vtv;
            for (int c=j;c<7;c++){
                double s=0.0; for (int i=j;i<15;i++) s += v[i]*M[i][c];
                s *= tau;
                for (int i=j;i<15;i++) M[i][c] -= s*v[i];
            }
            for (int c=0;c<7;c++){
                double s=0.0; for (int i=j;i<15;i++) s += v[i]*T[i][c];
                s *= tau;
                for (int i=j;i<15;i++) T[i][c] -= s*v[i];
            }
        }
        M[j][j] = alpha;
        for (int i=j+1;i<15;i++) M[i][j]=0.0;
    }
    double btd[49];
    for (int c=0;c<7;c++){
        double xs[7];
        for (int i=6;i>=0;i--){
            double s = T[i][c];
            for (int k2=i+1;k2<7;k2++) s -= M[i][k2]*xs[k2];
            xs[i] = s / M[i][i];
        }
        for (int i=0;i<7;i++) btd[i*7+c] = xs[i];
    }
    for (int i=0;i<49;i++) ka->bt[i] = (float)btd[i];
    double mb = 0.0;
    for (int v=0;v<7;v++){
        double rs = 0.0;
        for (int c=0;c<7;c++) rs += fabs(btd[v*7+c]);
        if (rs > mb) mb = rs;
    }
    *dual = (mb * 128.0 > 8192.0);
    for (int v=0;v<7;v++){
        float s = ka->bt[v*7+0];
        for (int w=1;w<7;w++) s = s + ka->bt[v*7+w];
        ka->einit[v] = -128.f * s;
    }
}

// ---------------- Kernel: weight transform -> per-(step,ng12) 1KB frag layout ----------------
__global__ void wt16_kernel(const float* __restrict__ w, _Float16* __restrict__ W3) {
    int idx = blockIdx.x*256 + threadIdx.x;     // chunk id, < 7*6*12*64 = 32256
    if (idx >= 32256) return;
    const int lane = idx & 63;
    int t = idx >> 6;
    const int ng = t % 12; t /= 12;
    const int step = t % 6; t /= 6;
    const int v = t;
    const int l15 = lane & 15, g = lane >> 4;
    const int rr = step >> 1, ch = step & 1;
    const int o = ng*16 + l15;
    const float Gf[7][3] = {{1,0,0},{1,1,1},{1,-1,1},{1,2,4},{1,-2,4},{1,3,9},{0,0,1}};
    const float g0 = Gf[v][0], g1 = Gf[v][1], g2 = Gf[v][2];
    f16x8 outv;
    #pragma unroll
    for (int e = 0; e < 8; ++e) {
        const int c = ch*32 + g*8 + e;
        const float* wp = w + (((size_t)o*CIN + c)*3 + rr)*3;
        float val = wp[0]*g0 + wp[1]*g1 + wp[2]*g2;
        val = rintf(val);
        val = fminf(fmaxf(val, -32768.f), 32767.f);
        outv[e] = (_Float16)val;
    }
    *(f16x8*)(W3 + (size_t)idx*8) = outv;
}

// ---------------- Main kernel: all-v E-table + krow-shared A-frags (stride-12 windows) ----------------
// Wave tile: output frags k=0..3 (m' = k*16 + t, t<12 real). A-window(krow,chh) serves
// all (k,rr) with k+rr==krow -> 12 A-reads/v (was 18).

#define BLOAD(S, sl) do { \
    br[sl] = *(const f16x8*)(W + (size_t)((S)*12 + ng)*512 + lane*8); \
} while (0)

template<bool DUAL>
__global__ __launch_bounds__(768, 3)
void main_kernel(const float* __restrict__ x, const _Float16* __restrict__ W,
                 const KArgs ka,
                 const float* __restrict__ alpha, const float* __restrict__ beta,
                 const float* __restrict__ sfp, const float* __restrict__ sop,
                 float* __restrict__ out)
{
    extern __shared__ char lds[];
    constexpr int EHOFF = 0;
    constexpr int ELOFF = 65536;                       // dual only (7 planes + pad)
    constexpr int RAWOFF = 0;                          // overlay: consumed before E write
    constexpr int RAWSTR = 68;

    const int kq = blockIdx.x, n = blockIdx.y, k0 = kq*KR;
    const int tid = threadIdx.x;
    const int wid = tid >> 6, lane = tid & 63, l15 = lane & 15, g = lane >> 4;
    const int ng = wid;
    const int t_e = wid, cc = lane;

    // ---- B register ring (depth 6): issue ASAP ----
    f16x8 br[6];
    BLOAD(0, 0); BLOAD(1, 1); BLOAD(2, 2); BLOAD(3, 3); BLOAD(4, 4); BLOAD(5, 5);

    // ---- stage raw x rows (k0-1 .. k0+4) as biased u8, stride 68 ----
    #pragma unroll
    for (int j = 0; j < 7; ++j) {
        int idx = j*768 + tid;                   // < 5376 data words
        int row = idx / 14, w = idx - row*14;
        int krow = row >> 6;
        int ch = row & 63;
        int xr = k0 + krow - 1;
        u32 bword = 0x80808080u;
        if (xr >= 0 && xr < HWD) {
            const float4 vx = *(const float4*)(x + (((size_t)(n*CIN + ch))*HWD + xr)*HWD + w*4);
            bword = (u32)(int)(vx.x + 128.f) | ((u32)(int)(vx.y + 128.f) << 8)
                  | ((u32)(int)(vx.z + 128.f) << 16) | ((u32)(int)(vx.w + 128.f) << 24);
        }
        *(u32*)(lds + RAWOFF + row*RAWSTR + 4 + w*4) = bword;
    }
    #pragma unroll
    for (int jj = 0; jj < 2; ++jj) {             // pads: bytes 0..3, 60..67
        int p = jj*768 + tid;
        if (p < 1152) {
            int row = p/3, ws = p - row*3;
            int wb = (ws == 0) ? 0 : (56 + ws*4);
            *(u32*)(lds + RAWOFF + row*RAWSTR + wb) = 0x80808080u;
        }
    }
    WAITL(); SBAR();

    // ---- extract per-thread x window (t = wid, c = lane) into 12 packed u32 regs ----
    u32 xwL[6], xwH[6];
    {
        const int a0 = (5*t_e + 3) & ~7;
        const int sh = ((5*t_e + 3) & 7) * 8;
        #pragma unroll
        for (int krow = 0; krow < 6; ++krow) {
            const char* pb = lds + RAWOFF + (krow*64 + cc)*RAWSTR + a0;
            u64 lo = *(const u64*)pb;
            u64 hi = *(const u64*)(pb + 8);
            u64 wnd = (lo >> sh) | ((hi << 1) << (63 - sh));
            xwL[krow] = (u32)wnd;
            xwH[krow] = (u32)(wnd >> 32);
        }
    }
    WAITL(); SBAR();   // RAW fully consumed; E region (same bytes) may be written

    // ---- build the FULL E table (all 7 v) in LDS; rolled over v ----
    #pragma unroll 1
    for (int v = 0; v < 7; ++v) {
        const float b0 = ka.bt[v*7+0], b1 = ka.bt[v*7+1], b2 = ka.bt[v*7+2];
        const float b3 = ka.bt[v*7+3], b4 = ka.bt[v*7+4], b5 = ka.bt[v*7+5], b6 = ka.bt[v*7+6];
        const float einit = ka.einit[v];
        #pragma unroll
        for (int krow = 0; krow < 6; ++krow) {
            const u32 Aw = xwL[krow], Bw = xwH[krow];
            float e = einit;
            e = fmaf(b0, (float)(Aw & 255u),         e);
            e = fmaf(b1, (float)((Aw >> 8) & 255u),  e);
            e = fmaf(b2, (float)((Aw >> 16) & 255u), e);
            e = fmaf(b3, (float)(Aw >> 24),          e);
            e = fmaf(b4, (float)(Bw & 255u),         e);
            e = fmaf(b5, (float)((Bw >> 8) & 255u),  e);
            e = fmaf(b6, (float)((Bw >> 16) & 255u), e);
            e = rintf(e);
            e = fminf(fmaxf(e, -32768.f), 32767.f);
            const int row = krow*12 + t_e;
            const int sb = v*9216 + row*128 + ((((cc >> 3) ^ (row & 7)) << 4) | ((cc & 7) << 1));
            if (DUAL) {
                float ehs = rintf(e * (1.f/2048.f)) * 2048.f;
                *(_Float16*)(lds + EHOFF + sb) = (_Float16)ehs;
                *(_Float16*)(lds + ELOFF + sb) = (_Float16)(e - ehs);
            } else {
                *(_Float16*)(lds + EHOFF + sb) = (_Float16)e;
            }
        }
    }
    WAITL(); SBAR();    // E table published; no more barriers until epilogue

    // ---- accumulators: 4 k-frags (m' = k*16 + t) x 1 B-frag (16 cols) ----
    f32x4 yu[5][4], mv[4];
    #pragma unroll
    for (int u = 0; u < 5; ++u)
        #pragma unroll
        for (int f = 0; f < 4; ++f) yu[u][f] = f32x4{0.f,0.f,0.f,0.f};
    #pragma unroll
    for (int f = 0; f < 4; ++f) mv[f] = f32x4{0.f,0.f,0.f,0.f};

    // ---- barrier-free main loop: 7 v x (2 chh x 6 krow windows) ----
    // A-window(krow,chh) = table rows krow*12 + p (p=0..15); serves rr with k=krow-rr.
    // Positions p>=12 are dead output lanes (harmless overlap into next krow's rows).
    #pragma unroll 1
    for (int v = 0; v < 7; ++v) {
        #pragma unroll
        for (int chh = 0; chh < 2; ++chh) {
            #pragma unroll
            for (int krow = 0; krow < 6; ++krow) {
                const int arow = krow*12 + l15;
                const int ab = v*9216 + arow*128 + ((((chh << 2) | g) ^ (arow & 7)) << 4);
                f16x8 af = *(const f16x8*)(lds + EHOFF + ab);
                if (krow <= 3)
                    mv[krow]   = __builtin_amdgcn_mfma_f32_16x16x32_f16(af, br[0 + chh], mv[krow],   0,0,0);
                if (krow >= 1 && krow <= 4)
                    mv[krow-1] = __builtin_amdgcn_mfma_f32_16x16x32_f16(af, br[2 + chh], mv[krow-1], 0,0,0);
                if (krow >= 2)
                    mv[krow-2] = __builtin_amdgcn_mfma_f32_16x16x32_f16(af, br[4 + chh], mv[krow-2], 0,0,0);
                if (DUAL) {
                    f16x8 al = *(const f16x8*)(lds + ELOFF + ab);
                    if (krow <= 3)
                        mv[krow]   = __builtin_amdgcn_mfma_f32_16x16x32_f16(al, br[0 + chh], mv[krow],   0,0,0);
                    if (krow >= 1 && krow <= 4)
                        mv[krow-1] = __builtin_amdgcn_mfma_f32_16x16x32_f16(al, br[2 + chh], mv[krow-1], 0,0,0);
                    if (krow >= 2)
                        mv[krow-2] = __builtin_amdgcn_mfma_f32_16x16x32_f16(al, br[4 + chh], mv[krow-2], 0,0,0);
                }
                // refill slot (rr= krow-3, chh) right after its last use this v
                if (krow >= 3 && v < 6) {
                    const int sl = (krow - 3)*2 + chh;
                    BLOAD((v+1)*6 + sl, sl);
                }
            }
        }
        // FOLD(v): yu += ATT[v][u] * mv (4 frags)
        {
            const float a0c = ATT[v][0], a1c = ATT[v][1], a2c = ATT[v][2];
            const float a3c = ATT[v][3], a4c = ATT[v][4];
            #pragma unroll
            for (int f = 0; f < 4; ++f) {
                yu[0][f] += a0c * mv[f];
                yu[1][f] += a1c * mv[f];
                yu[2][f] += a2c * mv[f];
                yu[3][f] += a3c * mv[f];
                yu[4][f] += a4c * mv[f];
                mv[f] = f32x4{0.f,0.f,0.f,0.f};
            }
        }
    }

    SBAR();   // all waves done reading the E table; LDS reusable for epilogue

    // ---- epilogue: quantize to u8 in LDS, then coalesced aligned output pass ----
    // Frag kf holds rows m' = kf*16 + p, p = g*4+q; real iff p < 12 (g < 3).
    const float rdenom = 1.f / (120.f * sfp[0]);
    const int o = ng*16 + l15;
    const float avv = alpha[o];
    const float bev = rintf(beta[o] * sop[0]);
    unsigned char* ldsb = (unsigned char*)lds;    // [192][224]
    if (g < 3) {
        #pragma unroll
        for (int kf = 0; kf < 4; ++kf) {
            #pragma unroll
            for (int q = 0; q < 4; ++q) {
                const int t = g*4 + q;            // 0..11
                #pragma unroll
                for (int u = 0; u < 5; ++u) {
                    const int col = t*5 + u;
                    if (col < HWD) {
                        float yv = yu[u][kf][q];
                        yv = rintf(yv * rdenom);
                        yv = rintf(avv*yv) + bev;
                        yv = rintf(yv);
                        yv = fminf(fmaxf(yv, -128.f), 127.f);
                        yv = fmaxf(yv, 0.f);
                        ldsb[o*224 + kf*56 + col] = (unsigned char)(int)yv;
                    }
                }
            }
        }
    }
    WAITL(); SBAR();
    float* ob = out + ((size_t)(n*COUT))*3136 + k0*56;
    #pragma unroll
    for (int it = 0; it < 14; ++it) {
        int i = it*768 + tid;                     // < 10752 quads
        int o2 = i / 56, q4 = i - o2*56;
        u32 wb2 = *(const u32*)(ldsb + o2*224 + q4*4);
        float4 f;
        f.x = (float)(wb2 & 255u);
        f.y = (float)((wb2 >> 8) & 255u);
        f.z = (float)((wb2 >> 16) & 255u);
        f.w = (float)(wb2 >> 24);
        *(float4*)(ob + (size_t)o2*3136 + q4*4) = f;
    }
}

extern "C" void kernel_launch(void* const* d_in, const int* in_sizes, int n_in,
                              void* d_out, int out_size, void* d_ws, size_t ws_size,
                              hipStream_t stream) {
    const float* x      = (const float*)d_in[0];
    const float* weight = (const float*)d_in[1];
    const float* alpha  = (const float*)d_in[2];
    const float* beta   = (const float*)d_in[3];
    const float* sf     = (const float*)d_in[4];
    const float* so     = (const float*)d_in[5];
    float* out = (float*)d_out;

    _Float16* Wp = (_Float16*)((char*)d_ws + WS_W_OFF);

    KArgs ka;
    bool dual;
    host_compute_bt(&ka, &dual);

    wt16_kernel<<<(32256 + 255)/256, 256, 0, stream>>>(weight, Wp);

    dim3 grid(NKQ, NBATCH);
    if (dual) {
        (void)hipFuncSetAttribute((const void*)&main_kernel<true>,
                                  hipFuncAttributeMaxDynamicSharedMemorySize, 131072);
        main_kernel<true><<<grid, 768, 131072, stream>>>(x, Wp, ka, alpha, beta, sf, so, out);
    } else {
        (void)hipFuncSetAttribute((const void*)&main_kernel<false>,
                                  hipFuncAttributeMaxDynamicSharedMemorySize, 65536);
        main_kernel<false><<<grid, 768, 65536, stream>>>(x, Wp, ka, alpha, beta, sf, so, out);
    }
}